// Round 19
// baseline (587.411 us; speedup 1.0000x reference)
//
#include <hip/hip_runtime.h>
#include <stdint.h>

typedef __fp16   pkv2 __attribute__((ext_vector_type(2)));   // cvt_pkrtz result
typedef _Float16 h2   __attribute__((ext_vector_type(2)));   // fdot2 operand

// ---- f16 pair helpers ------------------------------------------------------
__device__ __forceinline__ uint32_t pk(float a, float b) {     // RTZ (fast path)
    union { pkv2 h; uint32_t u; } u;
    u.h = __builtin_amdgcn_cvt_pkrtz(a, b);
    return u.u;
}
__device__ __forceinline__ uint32_t pkrne(float a, float b) {  // RNE (weights)
    union { _Float16 f[2]; uint32_t u; } u;
    u.f[0] = (_Float16)a; u.f[1] = (_Float16)b;
    return u.u;
}
__device__ __forceinline__ float dot2u(uint32_t w, uint32_t xp, float c) {
    union { uint32_t u; h2 h; } a, b; a.u = w; b.u = xp;
    return __builtin_amdgcn_fdot2(a.h, b.h, c, false);
}
__device__ __forceinline__ void unpk(uint32_t u, float& a, float& b) {
    union { uint32_t u; h2 h; } x; x.u = u;
    a = (float)x.h.x; b = (float)x.h.y;
}

// ---- DPP row-of-16 sum (VALU pipe) -----------------------------------------
template<int CTRL>
__device__ __forceinline__ float dppAdd(float v) {
    int sh = __builtin_amdgcn_update_dpp(0, __float_as_int(v), CTRL, 0xF, 0xF, true);
    return v + __int_as_float(sh);
}
__device__ __forceinline__ float rowSum16(float v) {
    v = dppAdd<0xB1>(v);    // quad_perm xor1
    v = dppAdd<0x4E>(v);    // quad_perm xor2
    v = dppAdd<0x124>(v);   // row_ror:4
    v = dppAdd<0x128>(v);   // row_ror:8
    return v;
}

// ---------------------------------------------------------------------------
// State: psi as 4x4 complex matrix M; 32 floats, idx = (i*4+j)*2 + ri.
// Cl(4,1) ~= M4(C): e1=g0, e2=g5, e3=i*g1, e4=i*g2, e5=g3 (Dirac basis).
// GP(delta, psi) == M_delta * M_psi; |psi|_blade^2 == |M|_F^2 / 4.
// ---------------------------------------------------------------------------

// ---- complex 4x4 matmul: O = D * P  (256 fmaf) -----------------------------
__device__ __forceinline__ void gpC(const float* __restrict__ D,
                                    const float* __restrict__ P,
                                    float* __restrict__ O) {
#pragma unroll
    for (int i = 0; i < 4; ++i) {
#pragma unroll
        for (int j = 0; j < 4; ++j) {
            float re = 0.f, im = 0.f;
#pragma unroll
            for (int k = 0; k < 4; ++k) {
                const float dr = D[(i * 4 + k) * 2], di = D[(i * 4 + k) * 2 + 1];
                const float pr = P[(k * 4 + j) * 2], pi = P[(k * 4 + j) * 2 + 1];
                re = fmaf(dr, pr, re); re = fmaf(-di, pi, re);
                im = fmaf(dr, pi, im); im = fmaf(di, pr, im);
            }
            O[(i * 4 + j) * 2] = re; O[(i * 4 + j) * 2 + 1] = im;
        }
    }
}

// ---- single-step embed: ONE b128 record per entry, one D array -------------
// (Smaller live set than pair-embed: D+U+O ~ 96 regs -> fits the 3-wave cap.)
__device__ __forceinline__ void embed1(const uint32_t* __restrict__ wf,
                                       float4 xv, float2 xw,
                                       float* __restrict__ D) {
#pragma unroll
    for (int a = 0; a < 32; ++a) {
        uint4 r = *(const uint4*)(wf + a * 4);
        float w0, w1, w2, w3, w4, w5;
        unpk(r.x, w0, w1); unpk(r.y, w2, w3); unpk(r.z, w4, w5);
        float d = __uint_as_float(r.w);
        d = fmaf(xv.x, w0, d);  d = fmaf(xv.y, w1, d);
        d = fmaf(xv.z, w2, d);  d = fmaf(xv.w, w3, d);
        d = fmaf(xw.x, w4, d);  d = fmaf(xw.y, w5, d);
        D[a] = d;
    }
}

// blade-norm normalize in matrix coords: |psi|^2 = sumsq(M)/4
__device__ __forceinline__ void nrmF(float* __restrict__ v) {
    float s0 = 0.f, s1 = 0.f, s2 = 0.f, s3 = 0.f;
#pragma unroll
    for (int k = 0; k < 32; k += 4) {
        s0 = fmaf(v[k], v[k], s0);  s1 = fmaf(v[k + 1], v[k + 1], s1);
        s2 = fmaf(v[k + 2], v[k + 2], s2);  s3 = fmaf(v[k + 3], v[k + 3], s3);
    }
    float rs = rsqrtf(fmaf((s0 + s1) + (s2 + s3), 0.25f, 1e-12f));
#pragma unroll
    for (int k = 0; k < 32; ++k) v[k] *= rs;
}

// ---- Phase-B combine: R = D * unpack(f16 cell) -----------------------------
__device__ __forceinline__ void scanC(const float* __restrict__ D,
                                      const uint32_t* __restrict__ ps,
                                      float* __restrict__ R) {
    float p[32];
#pragma unroll
    for (int mq = 0; mq < 4; ++mq) {
        uint4 v = *(const uint4*)(ps + mq * 4);
        unpk(v.x, p[8 * mq + 0], p[8 * mq + 1]);
        unpk(v.y, p[8 * mq + 2], p[8 * mq + 3]);
        unpk(v.z, p[8 * mq + 4], p[8 * mq + 5]);
        unpk(v.w, p[8 * mq + 6], p[8 * mq + 7]);
    }
    gpC(D, p, R);
}

__device__ __forceinline__ void packTQ(const float* __restrict__ v,
                                       uint32_t* __restrict__ dst) {
#pragma unroll
    for (int mq = 0; mq < 4; ++mq)
        *(uint4*)(dst + mq * 4) =
            make_uint4(pk(v[8 * mq + 0], v[8 * mq + 1]), pk(v[8 * mq + 2], v[8 * mq + 3]),
                       pk(v[8 * mq + 4], v[8 * mq + 5]), pk(v[8 * mq + 6], v[8 * mq + 7]));
}

// ---- project raw M (f16-safe), W'_out from global/L1, DPP head-reduce ------
__device__ __forceinline__ float emitOut(const float* __restrict__ P,
                                         const uint32_t* __restrict__ woh,
                                         float4 xv, float2 xw,
                                         const float* __restrict__ bo,
                                         int h, int b, int n, int t,
                                         float* __restrict__ out) {
    float s0 = 0.f, s1 = 0.f, s2 = 0.f, s3 = 0.f;
#pragma unroll
    for (int k = 0; k < 32; k += 4) {
        s0 = fmaf(P[k], P[k], s0);  s1 = fmaf(P[k + 1], P[k + 1], s1);
        s2 = fmaf(P[k + 2], P[k + 2], s2);  s3 = fmaf(P[k + 3], P[k + 3], s3);
    }
    float rs = rsqrtf(fmaf((s0 + s1) + (s2 + s3), 0.25f, 1e-12f));
    uint32_t ph[16];
#pragma unroll
    for (int m = 0; m < 16; ++m) ph[m] = pk(P[2 * m], P[2 * m + 1]);   // raw
    float pd[6];
#pragma unroll
    for (int dd = 0; dd < 6; ++dd) {
        uint4 w0 = *(const uint4*)(woh + dd * 16);
        uint4 w1 = *(const uint4*)(woh + dd * 16 + 4);
        uint4 w2 = *(const uint4*)(woh + dd * 16 + 8);
        uint4 w3 = *(const uint4*)(woh + dd * 16 + 12);
        float a0 = dot2u(w0.x, ph[0], 0.f);
        a0 = dot2u(w0.y, ph[1], a0);  a0 = dot2u(w0.z, ph[2], a0);
        a0 = dot2u(w0.w, ph[3], a0);  a0 = dot2u(w1.x, ph[4], a0);
        a0 = dot2u(w1.y, ph[5], a0);  a0 = dot2u(w1.z, ph[6], a0);
        a0 = dot2u(w1.w, ph[7], a0);
        float a1 = dot2u(w2.x, ph[8], 0.f);
        a1 = dot2u(w2.y, ph[9], a1);  a1 = dot2u(w2.z, ph[10], a1);
        a1 = dot2u(w2.w, ph[11], a1); a1 = dot2u(w3.x, ph[12], a1);
        a1 = dot2u(w3.y, ph[13], a1); a1 = dot2u(w3.z, ph[14], a1);
        a1 = dot2u(w3.w, ph[15], a1);
        pd[dd] = rowSum16((a0 + a1) * rs);     // DPP reduce over 16 head-lanes
    }
    float v = pd[0] + xv.x + bo[0];
    v = (h == 1) ? pd[1] + xv.y + bo[1] : v;
    v = (h == 2) ? pd[2] + xv.z + bo[2] : v;
    v = (h == 3) ? pd[3] + xv.w + bo[3] : v;
    v = (h == 4) ? pd[4] + xw.x + bo[4] : v;
    v = (h == 5) ? pd[5] + xw.y + bo[5] : v;
    if (h < 6)
        out[(((size_t)b * 256 + t) * 64 + n) * 6 + h] = v;
    return rs;
}

// pair x load, chunk-padded sX (pad every 32 steps; pairs never straddle)
#define SXBASE(t) ((t) * 6 + ((t) >> 5) * 4)
#define LOADX2(t, xv1, xw1, xv2, xw2)                               \
    { float4 p0 = *(const float4*)&sX[SXBASE(t)];                   \
      float4 p1 = *(const float4*)&sX[SXBASE(t) + 4];               \
      float4 p2 = *(const float4*)&sX[SXBASE(t) + 8];               \
      xv1 = p0; xw1 = make_float2(p1.x, p1.y);                      \
      xv2 = make_float4(p1.z, p1.w, p2.x, p2.y);                    \
      xw2 = make_float2(p2.z, p2.w); }

// ---------------------------------------------------------------------------
// Prep: gamma tables + transform weights to matrix coords.
// wsWF: 512 records x 16B (8KB): {f16 w0..w5, f32 bias'}. wsWo: 6KB.
// (Transform verified correct rounds 16-18.)
// ---------------------------------------------------------------------------
__global__ void prep(const float* __restrict__ W_in, const float* __restrict__ b_in,
                     const float* __restrict__ W_out,
                     uint32_t* __restrict__ wsWF, uint32_t* __restrict__ wsWo) {
    __shared__ float Gre[32][16], Gim[32][16];
    const int tid = threadIdx.x;

    if (tid < 32) {
        // generators: e1=g0, e2=g5, e3=i*g1, e4=i*g2, e5=g3 (Dirac basis)
        float gre[5][16] = {{0}}, gim[5][16] = {{0}};
        gre[0][0] = 1;  gre[0][5] = 1;  gre[0][10] = -1; gre[0][15] = -1;  // g0
        gre[1][2] = 1;  gre[1][7] = 1;  gre[1][8] = 1;   gre[1][13] = 1;   // g5
        gim[2][3] = 1;  gim[2][6] = 1;  gim[2][9] = -1;  gim[2][12] = -1;  // i*g1
        gre[3][3] = 1;  gre[3][6] = -1; gre[3][9] = -1;  gre[3][12] = 1;   // i*g2
        gre[4][2] = 1;  gre[4][7] = -1; gre[4][8] = -1;  gre[4][13] = 1;   // g3
        float Mre[16] = {0}, Mim[16] = {0};
        Mre[0] = Mre[5] = Mre[10] = Mre[15] = 1.f;     // identity
        for (int g = 0; g < 5; ++g) {
            if (!(tid & (1 << g))) continue;
            float Rre[16], Rim[16];
            for (int i = 0; i < 4; ++i)
                for (int j = 0; j < 4; ++j) {
                    float r = 0.f, s = 0.f;
                    for (int k = 0; k < 4; ++k) {
                        r += Mre[i*4+k]*gre[g][k*4+j] - Mim[i*4+k]*gim[g][k*4+j];
                        s += Mre[i*4+k]*gim[g][k*4+j] + Mim[i*4+k]*gre[g][k*4+j];
                    }
                    Rre[i*4+j] = r; Rim[i*4+j] = s;
                }
            for (int e = 0; e < 16; ++e) { Mre[e] = Rre[e]; Mim[e] = Rim[e]; }
        }
        for (int e = 0; e < 16; ++e) { Gre[tid][e] = Mre[e]; Gim[tid][e] = Mim[e]; }
    }
    __syncthreads();

    // W'_in + bias' records: {f16 w0..w5 (RNE), f32 bias'} per entry
    for (int e = tid; e < 512; e += blockDim.x) {
        const int h = e >> 5, ent = e & 31;
        const int m = ent >> 1, ri = ent & 1;
        float wv[7];
        for (int d = 0; d < 7; ++d) {
            float acc = 0.f;
            for (int A = 0; A < 32; ++A) {
                const float g = ri ? Gim[A][m] : Gre[A][m];
                const float c = (d < 6) ? W_in[d * 512 + h * 32 + A] : b_in[h * 32 + A];
                acc = fmaf(c, g, acc);
            }
            wv[d] = acc;
        }
        if (ri == 0 && (m == 0 || m == 5 || m == 10 || m == 15))
            wv[6] += 1.f;                          // +e0 -> +Identity
        uint32_t* dst = wsWF + e * 4;
        dst[0] = pkrne(wv[0], wv[1]);
        dst[1] = pkrne(wv[2], wv[3]);
        dst[2] = pkrne(wv[4], wv[5]);
        dst[3] = __float_as_uint(wv[6]);
    }

    // W'_out records: V[e][d] = sum_A W_out[A][d] * comp(G_A)[e] / 4
    for (int e = tid; e < 256; e += blockDim.x) {
        const int h = e >> 4, m = e & 15;
        for (int d = 0; d < 6; ++d) {
            float vr = 0.f, vi = 0.f;
            for (int A = 0; A < 32; ++A) {
                const float w = W_out[(h * 32 + A) * 6 + d] * 0.25f;
                vr = fmaf(w, Gre[A][m], vr);
                vi = fmaf(w, Gim[A][m], vi);
            }
            wsWo[h * 96 + d * 16 + m] = pkrne(vr, vi);
        }
    }
}

// ---------------------------------------------------------------------------
// One block per chain (b,n). 256 threads = 16 heads x 16 chunks of 16 steps.
// vs r18: single-step embed (one D array; live set ~150) + VGPR cap 170 via
// amdgpu_num_vgpr -> 3 waves/SIMD; 4096 waves supply the occupancy.
// (NOT launch_bounds: its occupancy model halves the budget — r6/r10.)
// Weight LDS reads double (the deliberate trade: regs -> occupancy hides it).
// ---------------------------------------------------------------------------
__global__ __launch_bounds__(256)
__attribute__((amdgpu_num_vgpr(170)))
void versor(const float* __restrict__ x, const uint32_t* __restrict__ wsWF,
            const float* __restrict__ b_out,
            const uint32_t* __restrict__ wsWo, float* __restrict__ out) {
    __shared__ __align__(16) uint32_t sWF[16 * 132];     // [h](132): 32 ents x 4 u32
    __shared__ __align__(16) float    sX[256 * 6 + 32];  // [t](6), +4/32-step pad
    __shared__ __align__(16) uint32_t sTQ[16 * 324];     // [h](324)[c](20)

    const int tid = threadIdx.x;
    const int bid = blockIdx.x;
    const int chain = (bid & 7) * 128 + (bid >> 3);   // XCD-contiguous chains
    const int b = chain >> 6, n = chain & 63;

    // ---- stage: compact weight records and x ----
    for (int e = tid; e < 512; e += 256) {            // 512 records x 1 uint4
        const int h = e >> 5, a = e & 31;
        *(uint4*)&sWF[h * 132 + a * 4] = *(const uint4*)(wsWF + e * 4);
    }
    {
        const int r = tid;
        const float2* s2 = (const float2*)(x + (((size_t)b * 256 + r) * 64 + n) * 6);
        float2 a0 = s2[0], a1 = s2[1], a2 = s2[2];
        float* dst = &sX[SXBASE(r)];
        *(float2*)dst = a0; *(float2*)(dst + 2) = a1; *(float2*)(dst + 4) = a2;
    }

    const int h = tid & 15, c = tid >> 4;          // c in [0,16)
    float bo[6];
#pragma unroll
    for (int dd = 0; dd < 6; ++dd) bo[dd] = b_out[dd];
    __syncthreads();

    const uint32_t* wf  = &sWF[h * 132];
    const uint32_t* woh = wsWo + h * 96;
    uint32_t*       tqh = &sTQ[h * 324];
    const int t0 = c * 16;

    float U[32], O[32], D[32];
    float4 xv1, xv2; float2 xw1, xw2;

    // ---- Phase A: 16-step chunk product (single-step embeds) ----
    LOADX2(t0, xv1, xw1, xv2, xw2);
    embed1(wf, xv1, xw1, U);                       // psi after step 0 = delta0
    embed1(wf, xv2, xw2, D);
    gpC(D, U, O);                                  // psi after steps 0,1 -> O
#pragma unroll 1
    for (int q = 1; q < 8; ++q) {
        LOADX2(t0 + 2 * q, xv1, xw1, xv2, xw2);
        embed1(wf, xv1, xw1, D);
        gpC(D, O, U);
        embed1(wf, xv2, xw2, D);
        gpC(D, U, O);
        if ((q & 3) == 3) nrmF(O);                 // after steps 7, 15
    }
    packTQ(O, tqh + c * 20);
    __syncthreads();

    // ---- Phase B: Hillis-Steele inclusive scan over 16 chunks (per head) ----
#pragma unroll 1
    for (int r = 0; r < 4; ++r) {
        const int s = 1 << r;
        const bool act = (c >= s);
        float R[32];
        if (act) scanC(O, tqh + (c - s) * 20, R);  // mine (later) x earlier
        __syncthreads();
        if (act) {
            nrmF(R);
#pragma unroll
            for (int j = 0; j < 32; ++j) O[j] = R[j];
            packTQ(O, tqh + c * 20);
        }
        __syncthreads();
    }

    // ---- Phase C: replay chunk from exclusive prefix Q_c = P_{c-1} ----
    if (c == 0) {
#pragma unroll
        for (int j = 0; j < 32; ++j) U[j] = 0.f;
        U[0] = 1.f; U[10] = 1.f; U[20] = 1.f; U[30] = 1.f;   // identity matrix
    } else {
        const uint32_t* ps = tqh + (c - 1) * 20;
#pragma unroll
        for (int mq = 0; mq < 4; ++mq) {
            uint4 v = *(const uint4*)(ps + mq * 4);
            unpk(v.x, U[8 * mq + 0], U[8 * mq + 1]);
            unpk(v.y, U[8 * mq + 2], U[8 * mq + 3]);
            unpk(v.z, U[8 * mq + 4], U[8 * mq + 5]);
            unpk(v.w, U[8 * mq + 6], U[8 * mq + 7]);
        }
    }

#pragma unroll 1
    for (int q = 0; q < 8; ++q) {
        const int t = t0 + 2 * q;
        LOADX2(t, xv1, xw1, xv2, xw2);
        embed1(wf, xv1, xw1, D);
        gpC(D, U, O);
        emitOut(O, woh, xv1, xw1, bo, h, b, n, t, out);
        embed1(wf, xv2, xw2, D);
        gpC(D, O, U);
        float rs = emitOut(U, woh, xv2, xw2, bo, h, b, n, t + 1, out);
#pragma unroll
        for (int j = 0; j < 32; ++j) U[j] *= rs;   // every pair: f16-range-safe
    }
}

// ---------------------------------------------------------------------------
extern "C" void kernel_launch(void* const* d_in, const int* in_sizes, int n_in,
                              void* d_out, int out_size, void* d_ws, size_t ws_size,
                              hipStream_t stream) {
    const float* x     = (const float*)d_in[0];
    const float* W_in  = (const float*)d_in[1];
    const float* b_in  = (const float*)d_in[2];
    const float* W_out = (const float*)d_in[3];
    const float* b_out = (const float*)d_in[4];
    float* out = (float*)d_out;

    uint32_t* wsWF = (uint32_t*)d_ws;                     // 512*16B = 8 KB
    uint32_t* wsWo = (uint32_t*)((char*)d_ws + 8192);     // 16*96*4 = 6 KB

    prep<<<1, 128, 0, stream>>>(W_in, b_in, W_out, wsWF, wsWo);
    versor<<<1024, 256, 0, stream>>>(x, wsWF, b_out, wsWo, out);
}

// Round 20
// 159.125 us; speedup vs baseline: 3.6915x; 3.6915x over previous
//
#include <hip/hip_runtime.h>
#include <stdint.h>

typedef __fp16   pkv2 __attribute__((ext_vector_type(2)));   // cvt_pkrtz result
typedef _Float16 h2   __attribute__((ext_vector_type(2)));   // fdot2 operand

// ---- f16 pair helpers ------------------------------------------------------
__device__ __forceinline__ uint32_t pk(float a, float b) {     // RTZ (fast path)
    union { pkv2 h; uint32_t u; } u;
    u.h = __builtin_amdgcn_cvt_pkrtz(a, b);
    return u.u;
}
__device__ __forceinline__ uint32_t pkrne(float a, float b) {  // RNE (weights/x)
    union { _Float16 f[2]; uint32_t u; } u;
    u.f[0] = (_Float16)a; u.f[1] = (_Float16)b;
    return u.u;
}
__device__ __forceinline__ float dot2u(uint32_t w, uint32_t xp, float c) {
    union { uint32_t u; h2 h; } a, b; a.u = w; b.u = xp;
    return __builtin_amdgcn_fdot2(a.h, b.h, c, false);
}
__device__ __forceinline__ void unpk(uint32_t u, float& a, float& b) {
    union { uint32_t u; h2 h; } x; x.u = u;
    a = (float)x.h.x; b = (float)x.h.y;
}

// ---- DPP row-of-16 sum (VALU pipe) -----------------------------------------
template<int CTRL>
__device__ __forceinline__ float dppAdd(float v) {
    int sh = __builtin_amdgcn_update_dpp(0, __float_as_int(v), CTRL, 0xF, 0xF, true);
    return v + __int_as_float(sh);
}
__device__ __forceinline__ float rowSum16(float v) {
    v = dppAdd<0xB1>(v);    // quad_perm xor1
    v = dppAdd<0x4E>(v);    // quad_perm xor2
    v = dppAdd<0x124>(v);   // row_ror:4
    v = dppAdd<0x128>(v);   // row_ror:8
    return v;
}

// ---------------------------------------------------------------------------
// State: psi as 4x4 complex matrix M; 32 floats, idx = (i*4+j)*2 + ri.
// Cl(4,1) ~= M4(C): e1=g0, e2=g5, e3=i*g1, e4=i*g2, e5=g3 (Dirac basis).
// GP(delta, psi) == M_delta * M_psi; |psi|_blade^2 == |M|_F^2 / 4.
// ---------------------------------------------------------------------------

// ---- complex 4x4 matmul: O = D * P  (256 fmaf) -----------------------------
__device__ __forceinline__ void gpC(const float* __restrict__ D,
                                    const float* __restrict__ P,
                                    float* __restrict__ O) {
#pragma unroll
    for (int i = 0; i < 4; ++i) {
#pragma unroll
        for (int j = 0; j < 4; ++j) {
            float re = 0.f, im = 0.f;
#pragma unroll
            for (int k = 0; k < 4; ++k) {
                const float dr = D[(i * 4 + k) * 2], di = D[(i * 4 + k) * 2 + 1];
                const float pr = P[(k * 4 + j) * 2], pi = P[(k * 4 + j) * 2 + 1];
                re = fmaf(dr, pr, re); re = fmaf(-di, pi, re);
                im = fmaf(dr, pi, im); im = fmaf(di, pr, im);
            }
            O[(i * 4 + j) * 2] = re; O[(i * 4 + j) * 2 + 1] = im;
        }
    }
}

// ---- paired embed via dot2: 6 v_dot2_f32_f16 per entry per pair ------------
// Record: {f16 w0..w5, f32 bias'}; x pre-packed to f16 pairs (RNE) in sXh.
__device__ __forceinline__ void embedPairH(const uint32_t* __restrict__ wf,
                                           uint32_t xpa0, uint32_t xpa1, uint32_t xpa2,
                                           uint32_t xpb0, uint32_t xpb1, uint32_t xpb2,
                                           float* __restrict__ D1,
                                           float* __restrict__ D2) {
#pragma unroll
    for (int a = 0; a < 32; ++a) {
        uint4 r = *(const uint4*)(wf + a * 4);
        const float bias = __uint_as_float(r.w);
        float d1 = dot2u(r.x, xpa0, bias);
        d1 = dot2u(r.y, xpa1, d1);
        d1 = dot2u(r.z, xpa2, d1);
        float d2 = dot2u(r.x, xpb0, bias);
        d2 = dot2u(r.y, xpb1, d2);
        d2 = dot2u(r.z, xpb2, d2);
        D1[a] = d1; D2[a] = d2;
    }
}

// blade-norm normalize in matrix coords: |psi|^2 = sumsq(M)/4
__device__ __forceinline__ void nrmF(float* __restrict__ v) {
    float s0 = 0.f, s1 = 0.f, s2 = 0.f, s3 = 0.f;
#pragma unroll
    for (int k = 0; k < 32; k += 4) {
        s0 = fmaf(v[k], v[k], s0);  s1 = fmaf(v[k + 1], v[k + 1], s1);
        s2 = fmaf(v[k + 2], v[k + 2], s2);  s3 = fmaf(v[k + 3], v[k + 3], s3);
    }
    float rs = rsqrtf(fmaf((s0 + s1) + (s2 + s3), 0.25f, 1e-12f));
#pragma unroll
    for (int k = 0; k < 32; ++k) v[k] *= rs;
}

// ---- Phase-B combine: R = D * unpack(f16 cell) -----------------------------
__device__ __forceinline__ void scanC(const float* __restrict__ D,
                                      const uint32_t* __restrict__ ps,
                                      float* __restrict__ R) {
    float p[32];
#pragma unroll
    for (int mq = 0; mq < 4; ++mq) {
        uint4 v = *(const uint4*)(ps + mq * 4);
        unpk(v.x, p[8 * mq + 0], p[8 * mq + 1]);
        unpk(v.y, p[8 * mq + 2], p[8 * mq + 3]);
        unpk(v.z, p[8 * mq + 4], p[8 * mq + 5]);
        unpk(v.w, p[8 * mq + 6], p[8 * mq + 7]);
    }
    gpC(D, p, R);
}

__device__ __forceinline__ void packTQ(const float* __restrict__ v,
                                       uint32_t* __restrict__ dst) {
#pragma unroll
    for (int mq = 0; mq < 4; ++mq)
        *(uint4*)(dst + mq * 4) =
            make_uint4(pk(v[8 * mq + 0], v[8 * mq + 1]), pk(v[8 * mq + 2], v[8 * mq + 3]),
                       pk(v[8 * mq + 4], v[8 * mq + 5]), pk(v[8 * mq + 6], v[8 * mq + 7]));
}

// ---- project raw M (f16-safe), W'_out from global/L1, DPP head-reduce ------
__device__ __forceinline__ float emitOut(const float* __restrict__ P,
                                         const uint32_t* __restrict__ woh,
                                         float4 xv, float2 xw,
                                         const float* __restrict__ bo,
                                         int h, int b, int n, int t,
                                         float* __restrict__ out) {
    float s0 = 0.f, s1 = 0.f, s2 = 0.f, s3 = 0.f;
#pragma unroll
    for (int k = 0; k < 32; k += 4) {
        s0 = fmaf(P[k], P[k], s0);  s1 = fmaf(P[k + 1], P[k + 1], s1);
        s2 = fmaf(P[k + 2], P[k + 2], s2);  s3 = fmaf(P[k + 3], P[k + 3], s3);
    }
    float rs = rsqrtf(fmaf((s0 + s1) + (s2 + s3), 0.25f, 1e-12f));
    uint32_t ph[16];
#pragma unroll
    for (int m = 0; m < 16; ++m) ph[m] = pk(P[2 * m], P[2 * m + 1]);   // raw
    float pd[6];
#pragma unroll
    for (int dd = 0; dd < 6; ++dd) {
        uint4 w0 = *(const uint4*)(woh + dd * 16);
        uint4 w1 = *(const uint4*)(woh + dd * 16 + 4);
        uint4 w2 = *(const uint4*)(woh + dd * 16 + 8);
        uint4 w3 = *(const uint4*)(woh + dd * 16 + 12);
        float a0 = dot2u(w0.x, ph[0], 0.f);
        a0 = dot2u(w0.y, ph[1], a0);  a0 = dot2u(w0.z, ph[2], a0);
        a0 = dot2u(w0.w, ph[3], a0);  a0 = dot2u(w1.x, ph[4], a0);
        a0 = dot2u(w1.y, ph[5], a0);  a0 = dot2u(w1.z, ph[6], a0);
        a0 = dot2u(w1.w, ph[7], a0);
        float a1 = dot2u(w2.x, ph[8], 0.f);
        a1 = dot2u(w2.y, ph[9], a1);  a1 = dot2u(w2.z, ph[10], a1);
        a1 = dot2u(w2.w, ph[11], a1); a1 = dot2u(w3.x, ph[12], a1);
        a1 = dot2u(w3.y, ph[13], a1); a1 = dot2u(w3.z, ph[14], a1);
        a1 = dot2u(w3.w, ph[15], a1);
        pd[dd] = rowSum16((a0 + a1) * rs);     // DPP reduce over 16 head-lanes
    }
    float v = pd[0] + xv.x + bo[0];
    v = (h == 1) ? pd[1] + xv.y + bo[1] : v;
    v = (h == 2) ? pd[2] + xv.z + bo[2] : v;
    v = (h == 3) ? pd[3] + xv.w + bo[3] : v;
    v = (h == 4) ? pd[4] + xw.x + bo[4] : v;
    v = (h == 5) ? pd[5] + xw.y + bo[5] : v;
    if (h < 6)
        out[(((size_t)b * 256 + t) * 64 + n) * 6 + h] = v;
    return rs;
}

// f32 x pair load (Phase C emit), chunk-padded sX
#define SXBASE(t) ((t) * 6 + ((t) >> 5) * 4)
#define LOADX2(t, xv1, xw1, xv2, xw2)                               \
    { float4 p0 = *(const float4*)&sX[SXBASE(t)];                   \
      float4 p1 = *(const float4*)&sX[SXBASE(t) + 4];               \
      float4 p2 = *(const float4*)&sX[SXBASE(t) + 8];               \
      xv1 = p0; xw1 = make_float2(p1.x, p1.y);                      \
      xv2 = make_float4(p1.z, p1.w, p2.x, p2.y);                    \
      xw2 = make_float2(p2.z, p2.w); }

// packed f16-x pair load (embeds), chunk-padded sXh (3 u32/step)
#define SXHBASE(t) ((t) * 3 + ((t) >> 5) * 4)
#define LOADXH2(t, a0_, a1_, a2_, b0_, b1_, b2_)                    \
    { uint2 qa = *(const uint2*)&sXh[SXHBASE(t)];                   \
      uint2 qb = *(const uint2*)&sXh[SXHBASE(t) + 2];               \
      uint2 qc = *(const uint2*)&sXh[SXHBASE(t) + 4];               \
      a0_ = qa.x; a1_ = qa.y; a2_ = qb.x;                           \
      b0_ = qb.y; b1_ = qc.x; b2_ = qc.y; }

// ---------------------------------------------------------------------------
// Prep: gamma tables + transform weights to matrix coords.
// wsWF: 512 records x 16B (8KB): {f16 w0..w5, f32 bias'}. wsWo: 6KB.
// (Transform verified correct rounds 16-18.)
// ---------------------------------------------------------------------------
__global__ void prep(const float* __restrict__ W_in, const float* __restrict__ b_in,
                     const float* __restrict__ W_out,
                     uint32_t* __restrict__ wsWF, uint32_t* __restrict__ wsWo) {
    __shared__ float Gre[32][16], Gim[32][16];
    const int tid = threadIdx.x;

    if (tid < 32) {
        // generators: e1=g0, e2=g5, e3=i*g1, e4=i*g2, e5=g3 (Dirac basis)
        float gre[5][16] = {{0}}, gim[5][16] = {{0}};
        gre[0][0] = 1;  gre[0][5] = 1;  gre[0][10] = -1; gre[0][15] = -1;  // g0
        gre[1][2] = 1;  gre[1][7] = 1;  gre[1][8] = 1;   gre[1][13] = 1;   // g5
        gim[2][3] = 1;  gim[2][6] = 1;  gim[2][9] = -1;  gim[2][12] = -1;  // i*g1
        gre[3][3] = 1;  gre[3][6] = -1; gre[3][9] = -1;  gre[3][12] = 1;   // i*g2
        gre[4][2] = 1;  gre[4][7] = -1; gre[4][8] = -1;  gre[4][13] = 1;   // g3
        float Mre[16] = {0}, Mim[16] = {0};
        Mre[0] = Mre[5] = Mre[10] = Mre[15] = 1.f;     // identity
        for (int g = 0; g < 5; ++g) {
            if (!(tid & (1 << g))) continue;
            float Rre[16], Rim[16];
            for (int i = 0; i < 4; ++i)
                for (int j = 0; j < 4; ++j) {
                    float r = 0.f, s = 0.f;
                    for (int k = 0; k < 4; ++k) {
                        r += Mre[i*4+k]*gre[g][k*4+j] - Mim[i*4+k]*gim[g][k*4+j];
                        s += Mre[i*4+k]*gim[g][k*4+j] + Mim[i*4+k]*gre[g][k*4+j];
                    }
                    Rre[i*4+j] = r; Rim[i*4+j] = s;
                }
            for (int e = 0; e < 16; ++e) { Mre[e] = Rre[e]; Mim[e] = Rim[e]; }
        }
        for (int e = 0; e < 16; ++e) { Gre[tid][e] = Mre[e]; Gim[tid][e] = Mim[e]; }
    }
    __syncthreads();

    // W'_in + bias' records: {f16 w0..w5 (RNE), f32 bias'} per entry
    for (int e = tid; e < 512; e += blockDim.x) {
        const int h = e >> 5, ent = e & 31;
        const int m = ent >> 1, ri = ent & 1;
        float wv[7];
        for (int d = 0; d < 7; ++d) {
            float acc = 0.f;
            for (int A = 0; A < 32; ++A) {
                const float g = ri ? Gim[A][m] : Gre[A][m];
                const float c = (d < 6) ? W_in[d * 512 + h * 32 + A] : b_in[h * 32 + A];
                acc = fmaf(c, g, acc);
            }
            wv[d] = acc;
        }
        if (ri == 0 && (m == 0 || m == 5 || m == 10 || m == 15))
            wv[6] += 1.f;                          // +e0 -> +Identity
        uint32_t* dst = wsWF + e * 4;
        dst[0] = pkrne(wv[0], wv[1]);
        dst[1] = pkrne(wv[2], wv[3]);
        dst[2] = pkrne(wv[4], wv[5]);
        dst[3] = __float_as_uint(wv[6]);
    }

    // W'_out records: V[e][d] = sum_A W_out[A][d] * comp(G_A)[e] / 4
    for (int e = tid; e < 256; e += blockDim.x) {
        const int h = e >> 4, m = e & 15;
        for (int d = 0; d < 6; ++d) {
            float vr = 0.f, vi = 0.f;
            for (int A = 0; A < 32; ++A) {
                const float w = W_out[(h * 32 + A) * 6 + d] * 0.25f;
                vr = fmaf(w, Gre[A][m], vr);
                vi = fmaf(w, Gim[A][m], vi);
            }
            wsWo[h * 96 + d * 16 + m] = pkrne(vr, vi);
        }
    }
}

// ---------------------------------------------------------------------------
// One block per chain (b,n). 128 threads = 16 heads x 8 chunks of 32 steps.
// vs r18: embed uses v_dot2_f32_f16 on f16-packed x (staged once, RNE) — 6
// dot2/entry/pair vs 12 fma(+cvt). Occupancy fixed at 2 waves/SIMD (VGPR 256
// needed; 5 capped attempts all spilled — r6/r10/r11/r19).
// ---------------------------------------------------------------------------
__global__ __launch_bounds__(128, 1)
void versor(const float* __restrict__ x, const uint32_t* __restrict__ wsWF,
            const float* __restrict__ b_out,
            const uint32_t* __restrict__ wsWo, float* __restrict__ out) {
    __shared__ __align__(16) uint32_t sWF[16 * 132];     // [h](132): 32 ents x 4 u32
    __shared__ __align__(16) float    sX[256 * 6 + 32];  // f32 x, +4/chunk pad
    __shared__ __align__(16) uint32_t sXh[256 * 3 + 32]; // f16-pair x, +4/chunk pad
    __shared__ __align__(16) uint32_t sTQ[16 * 164];     // [h](164)[c](20)

    const int tid = threadIdx.x;
    const int bid = blockIdx.x;
    const int chain = (bid & 7) * 128 + (bid >> 3);   // XCD-contiguous chains
    const int b = chain >> 6, n = chain & 63;

    // ---- stage: compact weight records, f32 x, f16-packed x ----
    for (int e = tid; e < 512; e += 128) {            // 512 records x 1 uint4
        const int h = e >> 5, a = e & 31;
        *(uint4*)&sWF[h * 132 + a * 4] = *(const uint4*)(wsWF + e * 4);
    }
    for (int r = tid; r < 256; r += 128) {
        const float2* s2 = (const float2*)(x + (((size_t)b * 256 + r) * 64 + n) * 6);
        float2 a0 = s2[0], a1 = s2[1], a2 = s2[2];
        float* dst = &sX[SXBASE(r)];
        *(float2*)dst = a0; *(float2*)(dst + 2) = a1; *(float2*)(dst + 4) = a2;
        uint32_t* dh = &sXh[SXHBASE(r)];
        dh[0] = pkrne(a0.x, a0.y);
        dh[1] = pkrne(a1.x, a1.y);
        dh[2] = pkrne(a2.x, a2.y);
    }

    const int h = tid & 15, c = tid >> 4;          // c in [0,8)
    float bo[6];
#pragma unroll
    for (int dd = 0; dd < 6; ++dd) bo[dd] = b_out[dd];
    __syncthreads();

    const uint32_t* wf  = &sWF[h * 132];
    const uint32_t* woh = wsWo + h * 96;
    uint32_t*       tqh = &sTQ[h * 164];
    const int t0 = c * 32;

    float U[32], O[32], D1[32], D2[32];
    uint32_t xa0, xa1, xa2, xb0, xb1, xb2;

    // ---- Phase A: 32-step chunk product (16 pairs, renorm every 4 pairs) ----
    LOADXH2(t0, xa0, xa1, xa2, xb0, xb1, xb2);
    embedPairH(wf, xa0, xa1, xa2, xb0, xb1, xb2, D1, D2);
    gpC(D2, D1, U);                                // psi after steps 0,1
#pragma unroll 1
    for (int q = 1; q < 16; ++q) {
        LOADXH2(t0 + 2 * q, xa0, xa1, xa2, xb0, xb1, xb2);
        embedPairH(wf, xa0, xa1, xa2, xb0, xb1, xb2, D1, D2);
        gpC(D1, U, O);
        gpC(D2, O, U);
        if ((q & 3) == 3) nrmF(U);                 // after steps 7,15,23,31
    }
    packTQ(U, tqh + c * 20);
    __syncthreads();

    // ---- Phase B: Hillis-Steele inclusive scan over 8 chunks (per head) ----
#pragma unroll
    for (int j = 0; j < 32; ++j) O[j] = U[j];
#pragma unroll 1
    for (int r = 0; r < 3; ++r) {
        const int s = 1 << r;
        const bool act = (c >= s);
        float R[32];
        if (act) scanC(O, tqh + (c - s) * 20, R);  // mine (later) x earlier
        __syncthreads();
        if (act) {
            nrmF(R);
#pragma unroll
            for (int j = 0; j < 32; ++j) O[j] = R[j];
            packTQ(O, tqh + c * 20);
        }
        __syncthreads();
    }

    // ---- Phase C: replay chunk from exclusive prefix Q_c = P_{c-1} ----
    if (c == 0) {
#pragma unroll
        for (int j = 0; j < 32; ++j) U[j] = 0.f;
        U[0] = 1.f; U[10] = 1.f; U[20] = 1.f; U[30] = 1.f;   // identity matrix
    } else {
        const uint32_t* ps = tqh + (c - 1) * 20;
#pragma unroll
        for (int mq = 0; mq < 4; ++mq) {
            uint4 v = *(const uint4*)(ps + mq * 4);
            unpk(v.x, U[8 * mq + 0], U[8 * mq + 1]);
            unpk(v.y, U[8 * mq + 2], U[8 * mq + 3]);
            unpk(v.z, U[8 * mq + 4], U[8 * mq + 5]);
            unpk(v.w, U[8 * mq + 6], U[8 * mq + 7]);
        }
    }

#pragma unroll 1
    for (int q = 0; q < 16; ++q) {
        const int t = t0 + 2 * q;
        float4 xv1, xv2; float2 xw1, xw2;
        LOADX2(t, xv1, xw1, xv2, xw2);
        LOADXH2(t, xa0, xa1, xa2, xb0, xb1, xb2);
        embedPairH(wf, xa0, xa1, xa2, xb0, xb1, xb2, D1, D2);
        gpC(D1, U, O);
        emitOut(O, woh, xv1, xw1, bo, h, b, n, t, out);
        gpC(D2, O, U);
        float rs = emitOut(U, woh, xv2, xw2, bo, h, b, n, t + 1, out);
#pragma unroll
        for (int j = 0; j < 32; ++j) U[j] *= rs;   // every pair: f16-range-safe
    }
}

// ---------------------------------------------------------------------------
extern "C" void kernel_launch(void* const* d_in, const int* in_sizes, int n_in,
                              void* d_out, int out_size, void* d_ws, size_t ws_size,
                              hipStream_t stream) {
    const float* x     = (const float*)d_in[0];
    const float* W_in  = (const float*)d_in[1];
    const float* b_in  = (const float*)d_in[2];
    const float* W_out = (const float*)d_in[3];
    const float* b_out = (const float*)d_in[4];
    float* out = (float*)d_out;

    uint32_t* wsWF = (uint32_t*)d_ws;                     // 512*16B = 8 KB
    uint32_t* wsWo = (uint32_t*)((char*)d_ws + 8192);     // 16*96*4 = 6 KB

    prep<<<1, 128, 0, stream>>>(W_in, b_in, W_out, wsWF, wsWo);
    versor<<<1024, 128, 0, stream>>>(x, wsWF, b_out, wsWo, out);
}

// Round 21
// 157.265 us; speedup vs baseline: 3.7352x; 1.0118x over previous
//
#include <hip/hip_runtime.h>
#include <stdint.h>

typedef __fp16   pkv2 __attribute__((ext_vector_type(2)));   // cvt_pkrtz result
typedef _Float16 h2   __attribute__((ext_vector_type(2)));   // fdot2 operand

// ---- f16 pair helpers ------------------------------------------------------
__device__ __forceinline__ uint32_t pk(float a, float b) {     // RTZ (fast path)
    union { pkv2 h; uint32_t u; } u;
    u.h = __builtin_amdgcn_cvt_pkrtz(a, b);
    return u.u;
}
__device__ __forceinline__ uint32_t pkrne(float a, float b) {  // RNE (weights/x)
    union { _Float16 f[2]; uint32_t u; } u;
    u.f[0] = (_Float16)a; u.f[1] = (_Float16)b;
    return u.u;
}
__device__ __forceinline__ float dot2u(uint32_t w, uint32_t xp, float c) {
    union { uint32_t u; h2 h; } a, b; a.u = w; b.u = xp;
    return __builtin_amdgcn_fdot2(a.h, b.h, c, false);
}
__device__ __forceinline__ void unpk(uint32_t u, float& a, float& b) {
    union { uint32_t u; h2 h; } x; x.u = u;
    a = (float)x.h.x; b = (float)x.h.y;
}

// ---- DPP row-of-16 sum (VALU pipe) -----------------------------------------
template<int CTRL>
__device__ __forceinline__ float dppAdd(float v) {
    int sh = __builtin_amdgcn_update_dpp(0, __float_as_int(v), CTRL, 0xF, 0xF, true);
    return v + __int_as_float(sh);
}
__device__ __forceinline__ float rowSum16(float v) {
    v = dppAdd<0xB1>(v);    // quad_perm xor1
    v = dppAdd<0x4E>(v);    // quad_perm xor2
    v = dppAdd<0x124>(v);   // row_ror:4
    v = dppAdd<0x128>(v);   // row_ror:8
    return v;
}

// ---------------------------------------------------------------------------
// State: psi as 4x4 complex matrix M; 32 floats, idx = (i*4+j)*2 + ri.
// Cl(4,1) ~= M4(C): e1=g0, e2=g5, e3=i*g1, e4=i*g2, e5=g3 (Dirac basis).
// GP(delta, psi) == M_delta * M_psi; |psi|_blade^2 == |M|_F^2 / 4.
// ---------------------------------------------------------------------------

// ---- complex 4x4 matmul: O = D * P  (256 fmaf) -----------------------------
__device__ __forceinline__ void gpC(const float* __restrict__ D,
                                    const float* __restrict__ P,
                                    float* __restrict__ O) {
#pragma unroll
    for (int i = 0; i < 4; ++i) {
#pragma unroll
        for (int j = 0; j < 4; ++j) {
            float re = 0.f, im = 0.f;
#pragma unroll
            for (int k = 0; k < 4; ++k) {
                const float dr = D[(i * 4 + k) * 2], di = D[(i * 4 + k) * 2 + 1];
                const float pr = P[(k * 4 + j) * 2], pi = P[(k * 4 + j) * 2 + 1];
                re = fmaf(dr, pr, re); re = fmaf(-di, pi, re);
                im = fmaf(dr, pi, im); im = fmaf(di, pr, im);
            }
            O[(i * 4 + j) * 2] = re; O[(i * 4 + j) * 2 + 1] = im;
        }
    }
}

// ---- paired embed via dot2: 6 v_dot2_f32_f16 per entry per pair ------------
// Record: {f16 w0..w5, f32 bias'}; x pre-packed to f16 pairs (RNE) in sXh.
__device__ __forceinline__ void embedPairH(const uint32_t* __restrict__ wf,
                                           uint32_t xpa0, uint32_t xpa1, uint32_t xpa2,
                                           uint32_t xpb0, uint32_t xpb1, uint32_t xpb2,
                                           float* __restrict__ D1,
                                           float* __restrict__ D2) {
#pragma unroll
    for (int a = 0; a < 32; ++a) {
        uint4 r = *(const uint4*)(wf + a * 4);
        const float bias = __uint_as_float(r.w);
        float d1 = dot2u(r.x, xpa0, bias);
        d1 = dot2u(r.y, xpa1, d1);
        d1 = dot2u(r.z, xpa2, d1);
        float d2 = dot2u(r.x, xpb0, bias);
        d2 = dot2u(r.y, xpb1, d2);
        d2 = dot2u(r.z, xpb2, d2);
        D1[a] = d1; D2[a] = d2;
    }
}

// blade-norm normalize in matrix coords: |psi|^2 = sumsq(M)/4
__device__ __forceinline__ void nrmF(float* __restrict__ v) {
    float s0 = 0.f, s1 = 0.f, s2 = 0.f, s3 = 0.f;
#pragma unroll
    for (int k = 0; k < 32; k += 4) {
        s0 = fmaf(v[k], v[k], s0);  s1 = fmaf(v[k + 1], v[k + 1], s1);
        s2 = fmaf(v[k + 2], v[k + 2], s2);  s3 = fmaf(v[k + 3], v[k + 3], s3);
    }
    float rs = rsqrtf(fmaf((s0 + s1) + (s2 + s3), 0.25f, 1e-12f));
#pragma unroll
    for (int k = 0; k < 32; ++k) v[k] *= rs;
}

// ---- Phase-B combine: R = D * unpack(f16 cell) -----------------------------
__device__ __forceinline__ void scanC(const float* __restrict__ D,
                                      const uint32_t* __restrict__ ps,
                                      float* __restrict__ R) {
    float p[32];
#pragma unroll
    for (int mq = 0; mq < 4; ++mq) {
        uint4 v = *(const uint4*)(ps + mq * 4);
        unpk(v.x, p[8 * mq + 0], p[8 * mq + 1]);
        unpk(v.y, p[8 * mq + 2], p[8 * mq + 3]);
        unpk(v.z, p[8 * mq + 4], p[8 * mq + 5]);
        unpk(v.w, p[8 * mq + 6], p[8 * mq + 7]);
    }
    gpC(D, p, R);
}

__device__ __forceinline__ void packTQ(const float* __restrict__ v,
                                       uint32_t* __restrict__ dst) {
#pragma unroll
    for (int mq = 0; mq < 4; ++mq)
        *(uint4*)(dst + mq * 4) =
            make_uint4(pk(v[8 * mq + 0], v[8 * mq + 1]), pk(v[8 * mq + 2], v[8 * mq + 3]),
                       pk(v[8 * mq + 4], v[8 * mq + 5]), pk(v[8 * mq + 6], v[8 * mq + 7]));
}

// ---- project raw M (f16-safe), W'_out from global/L1, DPP head-reduce ------
__device__ __forceinline__ float emitOut(const float* __restrict__ P,
                                         const uint32_t* __restrict__ woh,
                                         float4 xv, float2 xw,
                                         const float* __restrict__ bo,
                                         int h, int b, int n, int t,
                                         float* __restrict__ out) {
    float s0 = 0.f, s1 = 0.f, s2 = 0.f, s3 = 0.f;
#pragma unroll
    for (int k = 0; k < 32; k += 4) {
        s0 = fmaf(P[k], P[k], s0);  s1 = fmaf(P[k + 1], P[k + 1], s1);
        s2 = fmaf(P[k + 2], P[k + 2], s2);  s3 = fmaf(P[k + 3], P[k + 3], s3);
    }
    float rs = rsqrtf(fmaf((s0 + s1) + (s2 + s3), 0.25f, 1e-12f));
    uint32_t ph[16];
#pragma unroll
    for (int m = 0; m < 16; ++m) ph[m] = pk(P[2 * m], P[2 * m + 1]);   // raw
    float pd[6];
#pragma unroll
    for (int dd = 0; dd < 6; ++dd) {
        uint4 w0 = *(const uint4*)(woh + dd * 16);
        uint4 w1 = *(const uint4*)(woh + dd * 16 + 4);
        uint4 w2 = *(const uint4*)(woh + dd * 16 + 8);
        uint4 w3 = *(const uint4*)(woh + dd * 16 + 12);
        float a0 = dot2u(w0.x, ph[0], 0.f);
        a0 = dot2u(w0.y, ph[1], a0);  a0 = dot2u(w0.z, ph[2], a0);
        a0 = dot2u(w0.w, ph[3], a0);  a0 = dot2u(w1.x, ph[4], a0);
        a0 = dot2u(w1.y, ph[5], a0);  a0 = dot2u(w1.z, ph[6], a0);
        a0 = dot2u(w1.w, ph[7], a0);
        float a1 = dot2u(w2.x, ph[8], 0.f);
        a1 = dot2u(w2.y, ph[9], a1);  a1 = dot2u(w2.z, ph[10], a1);
        a1 = dot2u(w2.w, ph[11], a1); a1 = dot2u(w3.x, ph[12], a1);
        a1 = dot2u(w3.y, ph[13], a1); a1 = dot2u(w3.z, ph[14], a1);
        a1 = dot2u(w3.w, ph[15], a1);
        pd[dd] = rowSum16((a0 + a1) * rs);     // DPP reduce over 16 head-lanes
    }
    float v = pd[0] + xv.x + bo[0];
    v = (h == 1) ? pd[1] + xv.y + bo[1] : v;
    v = (h == 2) ? pd[2] + xv.z + bo[2] : v;
    v = (h == 3) ? pd[3] + xv.w + bo[3] : v;
    v = (h == 4) ? pd[4] + xw.x + bo[4] : v;
    v = (h == 5) ? pd[5] + xw.y + bo[5] : v;
    if (h < 6)
        out[(((size_t)b * 256 + t) * 64 + n) * 6 + h] = v;
    return rs;
}

// f32 x pair load (Phase C emit), chunk-padded sX
#define SXBASE(t) ((t) * 6 + ((t) >> 5) * 4)
#define LOADX2(t, xv1, xw1, xv2, xw2)                               \
    { float4 p0 = *(const float4*)&sX[SXBASE(t)];                   \
      float4 p1 = *(const float4*)&sX[SXBASE(t) + 4];               \
      float4 p2 = *(const float4*)&sX[SXBASE(t) + 8];               \
      xv1 = p0; xw1 = make_float2(p1.x, p1.y);                      \
      xv2 = make_float4(p1.z, p1.w, p2.x, p2.y);                    \
      xw2 = make_float2(p2.z, p2.w); }

// packed f16-x pair load (embeds), chunk-padded sXh (3 u32/step)
#define SXHBASE(t) ((t) * 3 + ((t) >> 5) * 4)
#define LOADXH2(t, a0_, a1_, a2_, b0_, b1_, b2_)                    \
    { uint2 qa = *(const uint2*)&sXh[SXHBASE(t)];                   \
      uint2 qb = *(const uint2*)&sXh[SXHBASE(t) + 2];               \
      uint2 qc = *(const uint2*)&sXh[SXHBASE(t) + 4];               \
      a0_ = qa.x; a1_ = qa.y; a2_ = qb.x;                           \
      b0_ = qb.y; b1_ = qc.x; b2_ = qc.y; }

// ---------------------------------------------------------------------------
// Prep: gamma tables + transform weights to matrix coords.
// wsWF: 512 records x 16B (8KB): {f16 w0..w5, f32 bias'}. wsWo: 6KB.
// (Transform verified correct rounds 16-20.)
// ---------------------------------------------------------------------------
__global__ void prep(const float* __restrict__ W_in, const float* __restrict__ b_in,
                     const float* __restrict__ W_out,
                     uint32_t* __restrict__ wsWF, uint32_t* __restrict__ wsWo) {
    __shared__ float Gre[32][16], Gim[32][16];
    const int tid = threadIdx.x;

    if (tid < 32) {
        // generators: e1=g0, e2=g5, e3=i*g1, e4=i*g2, e5=g3 (Dirac basis)
        float gre[5][16] = {{0}}, gim[5][16] = {{0}};
        gre[0][0] = 1;  gre[0][5] = 1;  gre[0][10] = -1; gre[0][15] = -1;  // g0
        gre[1][2] = 1;  gre[1][7] = 1;  gre[1][8] = 1;   gre[1][13] = 1;   // g5
        gim[2][3] = 1;  gim[2][6] = 1;  gim[2][9] = -1;  gim[2][12] = -1;  // i*g1
        gre[3][3] = 1;  gre[3][6] = -1; gre[3][9] = -1;  gre[3][12] = 1;   // i*g2
        gre[4][2] = 1;  gre[4][7] = -1; gre[4][8] = -1;  gre[4][13] = 1;   // g3
        float Mre[16] = {0}, Mim[16] = {0};
        Mre[0] = Mre[5] = Mre[10] = Mre[15] = 1.f;     // identity
        for (int g = 0; g < 5; ++g) {
            if (!(tid & (1 << g))) continue;
            float Rre[16], Rim[16];
            for (int i = 0; i < 4; ++i)
                for (int j = 0; j < 4; ++j) {
                    float r = 0.f, s = 0.f;
                    for (int k = 0; k < 4; ++k) {
                        r += Mre[i*4+k]*gre[g][k*4+j] - Mim[i*4+k]*gim[g][k*4+j];
                        s += Mre[i*4+k]*gim[g][k*4+j] + Mim[i*4+k]*gre[g][k*4+j];
                    }
                    Rre[i*4+j] = r; Rim[i*4+j] = s;
                }
            for (int e = 0; e < 16; ++e) { Mre[e] = Rre[e]; Mim[e] = Rim[e]; }
        }
        for (int e = 0; e < 16; ++e) { Gre[tid][e] = Mre[e]; Gim[tid][e] = Mim[e]; }
    }
    __syncthreads();

    // W'_in + bias' records: {f16 w0..w5 (RNE), f32 bias'} per entry
    for (int e = tid; e < 512; e += blockDim.x) {
        const int h = e >> 5, ent = e & 31;
        const int m = ent >> 1, ri = ent & 1;
        float wv[7];
        for (int d = 0; d < 7; ++d) {
            float acc = 0.f;
            for (int A = 0; A < 32; ++A) {
                const float g = ri ? Gim[A][m] : Gre[A][m];
                const float c = (d < 6) ? W_in[d * 512 + h * 32 + A] : b_in[h * 32 + A];
                acc = fmaf(c, g, acc);
            }
            wv[d] = acc;
        }
        if (ri == 0 && (m == 0 || m == 5 || m == 10 || m == 15))
            wv[6] += 1.f;                          // +e0 -> +Identity
        uint32_t* dst = wsWF + e * 4;
        dst[0] = pkrne(wv[0], wv[1]);
        dst[1] = pkrne(wv[2], wv[3]);
        dst[2] = pkrne(wv[4], wv[5]);
        dst[3] = __float_as_uint(wv[6]);
    }

    // W'_out records: V[e][d] = sum_A W_out[A][d] * comp(G_A)[e] / 4
    for (int e = tid; e < 256; e += blockDim.x) {
        const int h = e >> 4, m = e & 15;
        for (int d = 0; d < 6; ++d) {
            float vr = 0.f, vi = 0.f;
            for (int A = 0; A < 32; ++A) {
                const float w = W_out[(h * 32 + A) * 6 + d] * 0.25f;
                vr = fmaf(w, Gre[A][m], vr);
                vi = fmaf(w, Gim[A][m], vi);
            }
            wsWo[h * 96 + d * 16 + m] = pkrne(vr, vi);
        }
    }
}

// ---------------------------------------------------------------------------
// One block per chain (b,n). 128 threads = 16 heads x 8 chunks of 32 steps.
// vs r20: Phase A uses delta-tree per pair — E = D2*D1 computed OFF the
// U-chain, then one on-chain matmul U' = E*U (ping-pong U/O). Same inst
// count, half the loop-carried dependency depth. Phase C unchanged (needs
// intermediate psi for emit).
// ---------------------------------------------------------------------------
__global__ __launch_bounds__(128, 1)
void versor(const float* __restrict__ x, const uint32_t* __restrict__ wsWF,
            const float* __restrict__ b_out,
            const uint32_t* __restrict__ wsWo, float* __restrict__ out) {
    __shared__ __align__(16) uint32_t sWF[16 * 132];     // [h](132): 32 ents x 4 u32
    __shared__ __align__(16) float    sX[256 * 6 + 32];  // f32 x, +4/chunk pad
    __shared__ __align__(16) uint32_t sXh[256 * 3 + 32]; // f16-pair x, +4/chunk pad
    __shared__ __align__(16) uint32_t sTQ[16 * 164];     // [h](164)[c](20)

    const int tid = threadIdx.x;
    const int bid = blockIdx.x;
    const int chain = (bid & 7) * 128 + (bid >> 3);   // XCD-contiguous chains
    const int b = chain >> 6, n = chain & 63;

    // ---- stage: compact weight records, f32 x, f16-packed x ----
    for (int e = tid; e < 512; e += 128) {            // 512 records x 1 uint4
        const int h = e >> 5, a = e & 31;
        *(uint4*)&sWF[h * 132 + a * 4] = *(const uint4*)(wsWF + e * 4);
    }
    for (int r = tid; r < 256; r += 128) {
        const float2* s2 = (const float2*)(x + (((size_t)b * 256 + r) * 64 + n) * 6);
        float2 a0 = s2[0], a1 = s2[1], a2 = s2[2];
        float* dst = &sX[SXBASE(r)];
        *(float2*)dst = a0; *(float2*)(dst + 2) = a1; *(float2*)(dst + 4) = a2;
        uint32_t* dh = &sXh[SXHBASE(r)];
        dh[0] = pkrne(a0.x, a0.y);
        dh[1] = pkrne(a1.x, a1.y);
        dh[2] = pkrne(a2.x, a2.y);
    }

    const int h = tid & 15, c = tid >> 4;          // c in [0,8)
    float bo[6];
#pragma unroll
    for (int dd = 0; dd < 6; ++dd) bo[dd] = b_out[dd];
    __syncthreads();

    const uint32_t* wf  = &sWF[h * 132];
    const uint32_t* woh = wsWo + h * 96;
    uint32_t*       tqh = &sTQ[h * 164];
    const int t0 = c * 32;

    float U[32], O[32], D1[32], D2[32];
    uint32_t xa0, xa1, xa2, xb0, xb1, xb2;

    // ---- Phase A: 16 pairs, delta-tree (E=D2*D1 off-chain; 1 matmul/pair
    //      on the U-chain). State ping-pongs U -> O -> U ... ----
    {
        float E[32];
        LOADXH2(t0, xa0, xa1, xa2, xb0, xb1, xb2);
        embedPairH(wf, xa0, xa1, xa2, xb0, xb1, xb2, D1, D2);
        gpC(D2, D1, U);                            // pair 0: state U
#pragma unroll 1
        for (int qq = 0; qq < 7; ++qq) {
            const int p1 = 2 * qq + 1, p2 = 2 * qq + 2;
            LOADXH2(t0 + 2 * p1, xa0, xa1, xa2, xb0, xb1, xb2);
            embedPairH(wf, xa0, xa1, xa2, xb0, xb1, xb2, D1, D2);
            gpC(D2, D1, E);                        // off-chain
            gpC(E, U, O);                          // state O (pair p1)
            if (qq == 1 || qq == 3 || qq == 5) nrmF(O);   // after pairs 3,7,11
            LOADXH2(t0 + 2 * p2, xa0, xa1, xa2, xb0, xb1, xb2);
            embedPairH(wf, xa0, xa1, xa2, xb0, xb1, xb2, D1, D2);
            gpC(D2, D1, E);                        // off-chain
            gpC(E, O, U);                          // state U (pair p2)
        }
        LOADXH2(t0 + 30, xa0, xa1, xa2, xb0, xb1, xb2);
        embedPairH(wf, xa0, xa1, xa2, xb0, xb1, xb2, D1, D2);
        gpC(D2, D1, E);
        gpC(E, U, O);                              // pair 15: state O
        nrmF(O);
    }
    packTQ(O, tqh + c * 20);
    __syncthreads();

    // ---- Phase B: Hillis-Steele inclusive scan over 8 chunks (per head) ----
#pragma unroll 1
    for (int r = 0; r < 3; ++r) {
        const int s = 1 << r;
        const bool act = (c >= s);
        float R[32];
        if (act) scanC(O, tqh + (c - s) * 20, R);  // mine (later) x earlier
        __syncthreads();
        if (act) {
            nrmF(R);
#pragma unroll
            for (int j = 0; j < 32; ++j) O[j] = R[j];
            packTQ(O, tqh + c * 20);
        }
        __syncthreads();
    }

    // ---- Phase C: replay chunk from exclusive prefix Q_c = P_{c-1} ----
    if (c == 0) {
#pragma unroll
        for (int j = 0; j < 32; ++j) U[j] = 0.f;
        U[0] = 1.f; U[10] = 1.f; U[20] = 1.f; U[30] = 1.f;   // identity matrix
    } else {
        const uint32_t* ps = tqh + (c - 1) * 20;
#pragma unroll
        for (int mq = 0; mq < 4; ++mq) {
            uint4 v = *(const uint4*)(ps + mq * 4);
            unpk(v.x, U[8 * mq + 0], U[8 * mq + 1]);
            unpk(v.y, U[8 * mq + 2], U[8 * mq + 3]);
            unpk(v.z, U[8 * mq + 4], U[8 * mq + 5]);
            unpk(v.w, U[8 * mq + 6], U[8 * mq + 7]);
        }
    }

#pragma unroll 1
    for (int q = 0; q < 16; ++q) {
        const int t = t0 + 2 * q;
        float4 xv1, xv2; float2 xw1, xw2;
        LOADX2(t, xv1, xw1, xv2, xw2);
        LOADXH2(t, xa0, xa1, xa2, xb0, xb1, xb2);
        embedPairH(wf, xa0, xa1, xa2, xb0, xb1, xb2, D1, D2);
        gpC(D1, U, O);
        emitOut(O, woh, xv1, xw1, bo, h, b, n, t, out);
        gpC(D2, O, U);
        float rs = emitOut(U, woh, xv2, xw2, bo, h, b, n, t + 1, out);
#pragma unroll
        for (int j = 0; j < 32; ++j) U[j] *= rs;   // every pair: f16-range-safe
    }
}

// ---------------------------------------------------------------------------
extern "C" void kernel_launch(void* const* d_in, const int* in_sizes, int n_in,
                              void* d_out, int out_size, void* d_ws, size_t ws_size,
                              hipStream_t stream) {
    const float* x     = (const float*)d_in[0];
    const float* W_in  = (const float*)d_in[1];
    const float* b_in  = (const float*)d_in[2];
    const float* W_out = (const float*)d_in[3];
    const float* b_out = (const float*)d_in[4];
    float* out = (float*)d_out;

    uint32_t* wsWF = (uint32_t*)d_ws;                     // 512*16B = 8 KB
    uint32_t* wsWo = (uint32_t*)((char*)d_ws + 8192);     // 16*96*4 = 6 KB

    prep<<<1, 128, 0, stream>>>(W_in, b_in, W_out, wsWF, wsWo);
    versor<<<1024, 128, 0, stream>>>(x, wsWF, b_out, wsWo, out);
}